// Round 7
// baseline (179.346 us; speedup 1.0000x reference)
//
#include <hip/hip_runtime.h>

#define BSZ   2
#define LSEQ  2048
#define DQ    512
#define SQ    4
#define EPSQ  1e-6f

typedef float nfloat4 __attribute__((ext_vector_type(4)));  // native vec for nontemporal

struct Quat { float r, i, j, k; };

__device__ __forceinline__ Quat qmul(const Quat a, const Quat b) {
    Quat o;
    o.r = a.r*b.r - a.i*b.i - a.j*b.j - a.k*b.k;
    o.i = a.r*b.i + a.i*b.r + a.j*b.k - a.k*b.j;
    o.j = a.r*b.j - a.i*b.k + a.j*b.r + a.k*b.i;
    o.k = a.r*b.k + a.i*b.j - a.j*b.i + a.k*b.r;
    return o;
}

// a*b + c
__device__ __forceinline__ Quat qmuladd(const Quat a, const Quat b, const Quat c) {
    Quat o;
    o.r = c.r + a.r*b.r - a.i*b.i - a.j*b.j - a.k*b.k;
    o.i = c.i + a.r*b.i + a.i*b.r + a.j*b.k - a.k*b.j;
    o.j = c.j + a.r*b.j - a.i*b.k + a.j*b.r + a.k*b.i;
    o.k = c.k + a.r*b.k + a.i*b.j - a.j*b.i + a.k*b.r;
    return o;
}

__device__ __forceinline__ Quat q_of(const float4 v) { return Quat{v.x, v.y, v.z, v.w}; }
__device__ __forceinline__ float4 f4_of(const Quat q) { return make_float4(q.r, q.i, q.j, q.k); }

// Cayley transition q and input injection Bu from dt scalar a, hA = 0.5*A_quat.
// q  = s*(1-|w|^2, 2wi, 2wj, 2wk), w = a*hA, s = 1/((1-wr)^2+|w_im|^2+eps)
// Bu = (a*s) * (conj(den) x B) x u, conj(den) = (1-wr, wi, wj, wk)
__device__ __forceinline__ void cayley_step(const float a, const float4 hA,
                                            const float4 Bq, const float4 uq,
                                            Quat& q, Quat& Bu) {
    const float wr = a * hA.x;
    const float wi = a * hA.y;
    const float wj = a * hA.z;
    const float wk = a * hA.w;
    const float m  = wi*wi + wj*wj + wk*wk;
    const float e  = 1.0f - wr;
    const float dd = e*e + m + EPSQ;
    const float sv = __builtin_amdgcn_rcpf(dd);
    const float s2 = sv + sv;
    q.r = sv * (1.0f - (wr*wr + m));
    q.i = s2 * wi; q.j = s2 * wj; q.k = s2 * wk;
    const Quat cd{e, wi, wj, wk};
    const Quat cb = qmul(cd, q_of(Bq));
    const float as = a * sv;
    const Quat dB{as*cb.r, as*cb.i, as*cb.j, as*cb.k};
    Bu = qmul(dB, q_of(uq));
}

__device__ __forceinline__ float4 load_hA(const float* __restrict__ Alog,
                                          const float* __restrict__ Ai,
                                          const float* __restrict__ Aj,
                                          const float* __restrict__ Ak, int idx) {
    float4 hA;
    hA.x = -0.5f * __expf(Alog[idx]);
    hA.y =  0.5f * Ai[idx];
    hA.z =  0.5f * Aj[idx];
    hA.w =  0.5f * Ak[idx];
    return hA;
}

// ---------------- pass 1: chunk summaries, 2 s-channels per thread -----------
// grid: (DQ/256, NCH, BSZ*2), block 256. z encodes (b, s-half).
// __launch_bounds__(256,8): force VGPR<=64 so 8 waves/SIMD are resident
// (round-5 evidence: 124 VGPR -> 4 waves/SIMD, VALUBusy 54%).
// W layout: [b][s][c][d] float4
template<int NCH>
__global__ __launch_bounds__(256, 8) void qssm_pass1(
    const float* __restrict__ u, const float* __restrict__ dt,
    const float* __restrict__ Bin,
    const float* __restrict__ Alog, const float* __restrict__ Ai,
    const float* __restrict__ Aj,   const float* __restrict__ Ak,
    float4* __restrict__ WQ, float4* __restrict__ WB)
{
    constexpr int CH = LSEQ / NCH;
    const int d  = blockIdx.x * 256 + threadIdx.x;
    const int c  = blockIdx.y;
    const int b  = blockIdx.z >> 1;
    const int s0 = (blockIdx.z & 1) * 2;   // this block handles s0, s0+1
    const int t0 = c * CH;

    float4 hA[2];
    hA[0] = load_hA(Alog, Ai, Aj, Ak, d*SQ + s0);
    hA[1] = load_hA(Alog, Ai, Aj, Ak, d*SQ + s0 + 1);

    const int base = (b*LSEQ + t0);
    const float*  dtp = dt + (size_t)base*DQ + d;
    const float4* up  = (const float4*)u   + (size_t)base*DQ + d;
    const float4* Bp  = (const float4*)Bin + (size_t)base*SQ + s0;

    Quat Q[2], Bc[2];
    // peel j = 0 (summary starts at identity)
    {
        const float  a  = *dtp;
        const float4 uq = *up;
#pragma unroll
        for (int ss = 0; ss < 2; ++ss) {
            Quat q, Bu;
            cayley_step(a, hA[ss], Bp[ss], uq, q, Bu);
            Q[ss] = q; Bc[ss] = Bu;
        }
        dtp += DQ; up += DQ; Bp += SQ;
    }
#pragma unroll 2
    for (int j = 1; j < CH; ++j) {
        const float  a  = *dtp;
        const float4 uq = *up;
#pragma unroll
        for (int ss = 0; ss < 2; ++ss) {
            Quat q, Bu;
            cayley_step(a, hA[ss], Bp[ss], uq, q, Bu);
            Bc[ss] = qmuladd(q, Bc[ss], Bu);   // B' = q x B + Bu
            Q[ss]  = qmul(q, Q[ss]);           // Q' = q x Q
        }
        dtp += DQ; up += DQ; Bp += SQ;
    }
#pragma unroll
    for (int ss = 0; ss < 2; ++ss) {
        const size_t idx = ((size_t)(b*SQ + s0 + ss)*NCH + c)*DQ + d;
        WQ[idx] = f4_of(Q[ss]);
        WB[idx] = f4_of(Bc[ss]);
    }
}

// ---------------- pass 2: hierarchical scan, coalesced over d ----------------
// Block = 16 consecutive d-channels of one (b,s); thread (i = t&15, g = t>>4)
// owns superchunk g (GS=16 chunks). Loads are 256B-contiguous over the 16 d's.
// Overwrites WB[c] with h at chunk c's start.
template<int NCH>
__global__ __launch_bounds__(256) void qssm_pass2(
    const float4* __restrict__ WQ, float4* __restrict__ WB)
{
    constexpr int GS = 16;          // chunks per superchunk
    constexpr int NG = NCH / GS;    // superchunks per channel
    __shared__ float4 QL[NG][16];
    __shared__ float4 BL[NG][16];
    __shared__ float4 HS[NG][16];

    const int t  = threadIdx.x;
    const int i  = t & 15;          // local channel (d offset)
    const int g  = t >> 4;          // superchunk
    const int bs = blockIdx.x >> 5;             // (b*SQ+s), 0..7
    const int d  = (blockIdx.x & 31) * 16 + i;  // 0..511
    const size_t chbase = (size_t)bs * NCH * DQ + d;

    // step 1: compose chunks c = g*GS .. g*GS+GS-1 (earlier-first)
    size_t idx = chbase + (size_t)(g * GS) * DQ;
    Quat Qa = q_of(WQ[idx]);
    Quat Ba = q_of(WB[idx]);
#pragma unroll
    for (int j = 1; j < GS; ++j) {
        idx += DQ;
        const Quat Qc = q_of(WQ[idx]);
        const Quat Bc = q_of(WB[idx]);
        Ba = qmuladd(Qc, Ba, Bc);
        Qa = qmul(Qc, Qa);
    }
    QL[g][i] = f4_of(Qa);
    BL[g][i] = f4_of(Ba);
    __syncthreads();

    // step 2: 16 threads scan superchunk summaries (h0 = 0)
    if (t < 16) {
        Quat h{0.f, 0.f, 0.f, 0.f};
#pragma unroll
        for (int gg = 0; gg < NG; ++gg) {
            HS[gg][t] = f4_of(h);
            h = qmuladd(q_of(QL[gg][t]), h, q_of(BL[gg][t]));
        }
    }
    __syncthreads();

    // step 3: replay own superchunk, store h at each chunk start (in place)
    Quat h = q_of(HS[g][i]);
    idx = chbase + (size_t)(g * GS) * DQ;
#pragma unroll
    for (int j = 0; j < GS; ++j) {
        const Quat Qc = q_of(WQ[idx]);   // L2-hot re-read
        const Quat Bc = q_of(WB[idx]);
        WB[idx] = f4_of(h);
        h = qmuladd(Qc, h, Bc);
        idx += DQ;
    }
}

// ---------------- pass 3: replay with correct h_start, emit output -----------
// grid: (DQ/128, NCH, BSZ), block 256 = 4 waves. Each wave: 32 d x 2 s-halves
// (lane = 32*sh + dl). Partial y reduced across the halves via shfl_xor(32);
// lanes sh==0 store. Store addresses stay contiguous.
template<int NCH>
__global__ __launch_bounds__(256, 8) void qssm_pass3(
    const float* __restrict__ u, const float* __restrict__ dt,
    const float* __restrict__ Bin, const float* __restrict__ Cin,
    const float* __restrict__ Alog, const float* __restrict__ Ai,
    const float* __restrict__ Aj,   const float* __restrict__ Ak,
    const float4* __restrict__ WB, float* __restrict__ out)
{
    constexpr int CH = LSEQ / NCH;
    const int t    = threadIdx.x;
    const int lane = t & 63;
    const int wv   = t >> 6;
    const int dl   = lane & 31;
    const int sh   = lane >> 5;            // s-half: 0 or 1
    const int s0   = sh * 2;
    const int d = blockIdx.x * 128 + wv * 32 + dl;
    const int c = blockIdx.y;
    const int b = blockIdx.z;
    const int t0 = c * CH;

    float4 hA[2];
    Quat   h[2];
#pragma unroll
    for (int ss = 0; ss < 2; ++ss) {
        hA[ss] = load_hA(Alog, Ai, Aj, Ak, d*SQ + s0 + ss);
        h[ss] = q_of(WB[((size_t)(b*SQ + s0 + ss)*NCH + c)*DQ + d]);
    }
    const int base = (b*LSEQ + t0);
    const float*  dtp  = dt + (size_t)base*DQ + d;
    const float4* up   = (const float4*)u   + (size_t)base*DQ + d;
    const float4* Bp   = (const float4*)Bin + (size_t)base*SQ + s0;
    const float4* Cp   = (const float4*)Cin + (size_t)base*SQ + s0;
    nfloat4*      outp = (nfloat4*)out + (size_t)base*DQ + d;

#pragma unroll 2
    for (int j = 0; j < CH; ++j) {
        const float  a  = *dtp;
        const float4 uq = *up;
        Quat y{0.f, 0.f, 0.f, 0.f};
#pragma unroll
        for (int ss = 0; ss < 2; ++ss) {
            const float4 Cq = Cp[ss];
            Quat q, Bu;
            cayley_step(a, hA[ss], Bp[ss], uq, q, Bu);
            h[ss] = qmuladd(q, h[ss], Bu);
            y = qmuladd(q_of(Cq), h[ss], y);
        }
        // reduce partial y across the two s-halves (lanes l and l^32)
        y.r += __shfl_xor(y.r, 32);
        y.i += __shfl_xor(y.i, 32);
        y.j += __shfl_xor(y.j, 32);
        y.k += __shfl_xor(y.k, 32);
        if (sh == 0) {
            const nfloat4 yv = {y.r, y.i, y.j, y.k};
            __builtin_nontemporal_store(yv, outp);  // out never re-read
        }
        dtp += DQ; up += DQ; Bp += SQ; Cp += SQ; outp += DQ;
    }
}

template<int NCH>
static void launch_all(const float* u, const float* dt, const float* Bin,
                       const float* Cin, const float* Alog, const float* Ai,
                       const float* Aj, const float* Ak,
                       float* out, void* d_ws, hipStream_t stream) {
    const size_t elems = (size_t)BSZ * SQ * NCH * DQ;
    float4* WQ = (float4*)d_ws;
    float4* WB = WQ + elems;
    dim3 g1(DQ / 256, NCH, BSZ * 2);
    qssm_pass1<NCH><<<g1, 256, 0, stream>>>(u, dt, Bin, Alog, Ai, Aj, Ak, WQ, WB);
    qssm_pass2<NCH><<<(BSZ*SQ*DQ)/16, 16*(NCH/16), 0, stream>>>(WQ, WB);
    dim3 g3(DQ / 128, NCH, BSZ);
    qssm_pass3<NCH><<<g3, 256, 0, stream>>>(u, dt, Bin, Cin, Alog, Ai, Aj, Ak, WB, out);
}

extern "C" void kernel_launch(void* const* d_in, const int* in_sizes, int n_in,
                              void* d_out, int out_size, void* d_ws, size_t ws_size,
                              hipStream_t stream) {
    const float* u    = (const float*)d_in[0];
    const float* dt   = (const float*)d_in[1];
    const float* Bin  = (const float*)d_in[2];
    const float* Cin  = (const float*)d_in[3];
    const float* Alog = (const float*)d_in[4];
    const float* Ai   = (const float*)d_in[5];
    const float* Aj   = (const float*)d_in[6];
    const float* Ak   = (const float*)d_in[7];
    float* out = (float*)d_out;

    auto ws_need = [](int nch) -> size_t {
        return 2ull * BSZ * SQ * (size_t)nch * DQ * sizeof(float4);
    };
    if (ws_size >= ws_need(256)) {
        launch_all<256>(u, dt, Bin, Cin, Alog, Ai, Aj, Ak, out, d_ws, stream);
    } else if (ws_size >= ws_need(128)) {
        launch_all<128>(u, dt, Bin, Cin, Alog, Ai, Aj, Ak, out, d_ws, stream);
    } else {
        launch_all<64>(u, dt, Bin, Cin, Alog, Ai, Aj, Ak, out, d_ws, stream);
    }
}

// Round 8
// 160.529 us; speedup vs baseline: 1.1172x; 1.1172x over previous
//
#include <hip/hip_runtime.h>

#define BSZ   2
#define LSEQ  2048
#define DQ    512
#define SQ    4
#define EPSQ  1e-6f

typedef float nfloat4 __attribute__((ext_vector_type(4)));  // native vec for nontemporal

struct Quat { float r, i, j, k; };

__device__ __forceinline__ Quat qmul(const Quat a, const Quat b) {
    Quat o;
    o.r = a.r*b.r - a.i*b.i - a.j*b.j - a.k*b.k;
    o.i = a.r*b.i + a.i*b.r + a.j*b.k - a.k*b.j;
    o.j = a.r*b.j - a.i*b.k + a.j*b.r + a.k*b.i;
    o.k = a.r*b.k + a.i*b.j - a.j*b.i + a.k*b.r;
    return o;
}

// a*b + c
__device__ __forceinline__ Quat qmuladd(const Quat a, const Quat b, const Quat c) {
    Quat o;
    o.r = c.r + a.r*b.r - a.i*b.i - a.j*b.j - a.k*b.k;
    o.i = c.i + a.r*b.i + a.i*b.r + a.j*b.k - a.k*b.j;
    o.j = c.j + a.r*b.j - a.i*b.k + a.j*b.r + a.k*b.i;
    o.k = c.k + a.r*b.k + a.i*b.j - a.j*b.i + a.k*b.r;
    return o;
}

__device__ __forceinline__ Quat q_of(const float4 v) { return Quat{v.x, v.y, v.z, v.w}; }
__device__ __forceinline__ float4 f4_of(const Quat q) { return make_float4(q.r, q.i, q.j, q.k); }

// Cayley transition q and input injection Bu from dt scalar a, hA = 0.5*A_quat.
// q  = s*(1-|w|^2, 2wi, 2wj, 2wk), w = a*hA, s = 1/((1-wr)^2+|w_im|^2+eps)
// Bu = (a*s) * (conj(den) x B) x u, conj(den) = (1-wr, wi, wj, wk)
__device__ __forceinline__ void cayley_step(const float a, const float4 hA,
                                            const float4 Bq, const float4 uq,
                                            Quat& q, Quat& Bu) {
    const float wr = a * hA.x;
    const float wi = a * hA.y;
    const float wj = a * hA.z;
    const float wk = a * hA.w;
    const float m  = wi*wi + wj*wj + wk*wk;
    const float e  = 1.0f - wr;
    const float dd = e*e + m + EPSQ;
    const float sv = __builtin_amdgcn_rcpf(dd);
    const float s2 = sv + sv;
    q.r = sv * (1.0f - (wr*wr + m));
    q.i = s2 * wi; q.j = s2 * wj; q.k = s2 * wk;
    const Quat cd{e, wi, wj, wk};
    const Quat cb = qmul(cd, q_of(Bq));
    const float as = a * sv;
    const Quat dB{as*cb.r, as*cb.i, as*cb.j, as*cb.k};
    Bu = qmul(dB, q_of(uq));
}

__device__ __forceinline__ float4 load_hA(const float* __restrict__ Alog,
                                          const float* __restrict__ Ai,
                                          const float* __restrict__ Aj,
                                          const float* __restrict__ Ak, int idx) {
    float4 hA;
    hA.x = -0.5f * __expf(Alog[idx]);
    hA.y =  0.5f * Ai[idx];
    hA.z =  0.5f * Aj[idx];
    hA.w =  0.5f * Ak[idx];
    return hA;
}

// ---------------- pass 1: chunk summaries, 2 s-channels per thread -----------
// grid: (DQ/256, NCH, BSZ*2), block 256. z encodes (b, s-half).
// __launch_bounds__(256,6): cap at ~85 VGPR -> 6 waves/SIMD. (256,8) forced a
// spill collapse (round 7: VGPR=32, +52MB scratch traffic, pass3 41->50us).
// W layout: [b][s][c][d] float4
template<int NCH>
__global__ __launch_bounds__(256, 6) void qssm_pass1(
    const float* __restrict__ u, const float* __restrict__ dt,
    const float* __restrict__ Bin,
    const float* __restrict__ Alog, const float* __restrict__ Ai,
    const float* __restrict__ Aj,   const float* __restrict__ Ak,
    float4* __restrict__ WQ, float4* __restrict__ WB)
{
    constexpr int CH = LSEQ / NCH;
    const int d  = blockIdx.x * 256 + threadIdx.x;
    const int c  = blockIdx.y;
    const int b  = blockIdx.z >> 1;
    const int s0 = (blockIdx.z & 1) * 2;   // this block handles s0, s0+1
    const int t0 = c * CH;

    float4 hA[2];
    hA[0] = load_hA(Alog, Ai, Aj, Ak, d*SQ + s0);
    hA[1] = load_hA(Alog, Ai, Aj, Ak, d*SQ + s0 + 1);

    const int base = (b*LSEQ + t0);
    const float*  dtp = dt + (size_t)base*DQ + d;
    const float4* up  = (const float4*)u   + (size_t)base*DQ + d;
    const float4* Bp  = (const float4*)Bin + (size_t)base*SQ + s0;

    Quat Q[2], Bc[2];
    // peel j = 0 (summary starts at identity)
    {
        const float  a  = *dtp;
        const float4 uq = *up;
#pragma unroll
        for (int ss = 0; ss < 2; ++ss) {
            Quat q, Bu;
            cayley_step(a, hA[ss], Bp[ss], uq, q, Bu);
            Q[ss] = q; Bc[ss] = Bu;
        }
        dtp += DQ; up += DQ; Bp += SQ;
    }
#pragma unroll 2
    for (int j = 1; j < CH; ++j) {
        const float  a  = *dtp;
        const float4 uq = *up;
#pragma unroll
        for (int ss = 0; ss < 2; ++ss) {
            Quat q, Bu;
            cayley_step(a, hA[ss], Bp[ss], uq, q, Bu);
            Bc[ss] = qmuladd(q, Bc[ss], Bu);   // B' = q x B + Bu
            Q[ss]  = qmul(q, Q[ss]);           // Q' = q x Q
        }
        dtp += DQ; up += DQ; Bp += SQ;
    }
#pragma unroll
    for (int ss = 0; ss < 2; ++ss) {
        const size_t idx = ((size_t)(b*SQ + s0 + ss)*NCH + c)*DQ + d;
        WQ[idx] = f4_of(Q[ss]);
        WB[idx] = f4_of(Bc[ss]);
    }
}

// ---------------- pass 2: hierarchical scan, coalesced over d ----------------
// Block = 16 consecutive d-channels of one (b,s); thread (i = t&15, g = t>>4)
// owns superchunk g (GS=16 chunks). Loads are 256B-contiguous over the 16 d's.
// Overwrites WB[c] with h at chunk c's start.
template<int NCH>
__global__ __launch_bounds__(256) void qssm_pass2(
    const float4* __restrict__ WQ, float4* __restrict__ WB)
{
    constexpr int GS = 16;          // chunks per superchunk
    constexpr int NG = NCH / GS;    // superchunks per channel
    __shared__ float4 QL[NG][16];
    __shared__ float4 BL[NG][16];
    __shared__ float4 HS[NG][16];

    const int t  = threadIdx.x;
    const int i  = t & 15;          // local channel (d offset)
    const int g  = t >> 4;          // superchunk
    const int bs = blockIdx.x >> 5;             // (b*SQ+s), 0..7
    const int d  = (blockIdx.x & 31) * 16 + i;  // 0..511
    const size_t chbase = (size_t)bs * NCH * DQ + d;

    // step 1: compose chunks c = g*GS .. g*GS+GS-1 (earlier-first)
    size_t idx = chbase + (size_t)(g * GS) * DQ;
    Quat Qa = q_of(WQ[idx]);
    Quat Ba = q_of(WB[idx]);
#pragma unroll
    for (int j = 1; j < GS; ++j) {
        idx += DQ;
        const Quat Qc = q_of(WQ[idx]);
        const Quat Bc = q_of(WB[idx]);
        Ba = qmuladd(Qc, Ba, Bc);
        Qa = qmul(Qc, Qa);
    }
    QL[g][i] = f4_of(Qa);
    BL[g][i] = f4_of(Ba);
    __syncthreads();

    // step 2: 16 threads scan superchunk summaries (h0 = 0)
    if (t < 16) {
        Quat h{0.f, 0.f, 0.f, 0.f};
#pragma unroll
        for (int gg = 0; gg < NG; ++gg) {
            HS[gg][t] = f4_of(h);
            h = qmuladd(q_of(QL[gg][t]), h, q_of(BL[gg][t]));
        }
    }
    __syncthreads();

    // step 3: replay own superchunk, store h at each chunk start (in place)
    Quat h = q_of(HS[g][i]);
    idx = chbase + (size_t)(g * GS) * DQ;
#pragma unroll
    for (int j = 0; j < GS; ++j) {
        const Quat Qc = q_of(WQ[idx]);   // L2-hot re-read
        const Quat Bc = q_of(WB[idx]);
        WB[idx] = f4_of(h);
        h = qmuladd(Qc, h, Bc);
        idx += DQ;
    }
}

// ---------------- pass 3: replay with correct h_start, emit output -----------
// grid: (DQ/128, NCH, BSZ), block 256 = 4 waves. Each wave: 32 d x 2 s-halves
// (lane = 32*sh + dl). Partial y reduced across the halves via shfl_xor(32);
// lanes sh==0 store. Store addresses stay contiguous.
template<int NCH>
__global__ __launch_bounds__(256, 6) void qssm_pass3(
    const float* __restrict__ u, const float* __restrict__ dt,
    const float* __restrict__ Bin, const float* __restrict__ Cin,
    const float* __restrict__ Alog, const float* __restrict__ Ai,
    const float* __restrict__ Aj,   const float* __restrict__ Ak,
    const float4* __restrict__ WB, float* __restrict__ out)
{
    constexpr int CH = LSEQ / NCH;
    const int t    = threadIdx.x;
    const int lane = t & 63;
    const int wv   = t >> 6;
    const int dl   = lane & 31;
    const int sh   = lane >> 5;            // s-half: 0 or 1
    const int s0   = sh * 2;
    const int d = blockIdx.x * 128 + wv * 32 + dl;
    const int c = blockIdx.y;
    const int b = blockIdx.z;
    const int t0 = c * CH;

    float4 hA[2];
    Quat   h[2];
#pragma unroll
    for (int ss = 0; ss < 2; ++ss) {
        hA[ss] = load_hA(Alog, Ai, Aj, Ak, d*SQ + s0 + ss);
        h[ss] = q_of(WB[((size_t)(b*SQ + s0 + ss)*NCH + c)*DQ + d]);
    }
    const int base = (b*LSEQ + t0);
    const float*  dtp  = dt + (size_t)base*DQ + d;
    const float4* up   = (const float4*)u   + (size_t)base*DQ + d;
    const float4* Bp   = (const float4*)Bin + (size_t)base*SQ + s0;
    const float4* Cp   = (const float4*)Cin + (size_t)base*SQ + s0;
    nfloat4*      outp = (nfloat4*)out + (size_t)base*DQ + d;

#pragma unroll 2
    for (int j = 0; j < CH; ++j) {
        const float  a  = *dtp;
        const float4 uq = *up;
        Quat y{0.f, 0.f, 0.f, 0.f};
#pragma unroll
        for (int ss = 0; ss < 2; ++ss) {
            const float4 Cq = Cp[ss];
            Quat q, Bu;
            cayley_step(a, hA[ss], Bp[ss], uq, q, Bu);
            h[ss] = qmuladd(q, h[ss], Bu);
            y = qmuladd(q_of(Cq), h[ss], y);
        }
        // reduce partial y across the two s-halves (lanes l and l^32)
        y.r += __shfl_xor(y.r, 32);
        y.i += __shfl_xor(y.i, 32);
        y.j += __shfl_xor(y.j, 32);
        y.k += __shfl_xor(y.k, 32);
        if (sh == 0) {
            const nfloat4 yv = {y.r, y.i, y.j, y.k};
            __builtin_nontemporal_store(yv, outp);  // out never re-read
        }
        dtp += DQ; up += DQ; Bp += SQ; Cp += SQ; outp += DQ;
    }
}

template<int NCH>
static void launch_all(const float* u, const float* dt, const float* Bin,
                       const float* Cin, const float* Alog, const float* Ai,
                       const float* Aj, const float* Ak,
                       float* out, void* d_ws, hipStream_t stream) {
    const size_t elems = (size_t)BSZ * SQ * NCH * DQ;
    float4* WQ = (float4*)d_ws;
    float4* WB = WQ + elems;
    dim3 g1(DQ / 256, NCH, BSZ * 2);
    qssm_pass1<NCH><<<g1, 256, 0, stream>>>(u, dt, Bin, Alog, Ai, Aj, Ak, WQ, WB);
    qssm_pass2<NCH><<<(BSZ*SQ*DQ)/16, 16*(NCH/16), 0, stream>>>(WQ, WB);
    dim3 g3(DQ / 128, NCH, BSZ);
    qssm_pass3<NCH><<<g3, 256, 0, stream>>>(u, dt, Bin, Cin, Alog, Ai, Aj, Ak, WB, out);
}

extern "C" void kernel_launch(void* const* d_in, const int* in_sizes, int n_in,
                              void* d_out, int out_size, void* d_ws, size_t ws_size,
                              hipStream_t stream) {
    const float* u    = (const float*)d_in[0];
    const float* dt   = (const float*)d_in[1];
    const float* Bin  = (const float*)d_in[2];
    const float* Cin  = (const float*)d_in[3];
    const float* Alog = (const float*)d_in[4];
    const float* Ai   = (const float*)d_in[5];
    const float* Aj   = (const float*)d_in[6];
    const float* Ak   = (const float*)d_in[7];
    float* out = (float*)d_out;

    auto ws_need = [](int nch) -> size_t {
        return 2ull * BSZ * SQ * (size_t)nch * DQ * sizeof(float4);
    };
    if (ws_size >= ws_need(256)) {
        launch_all<256>(u, dt, Bin, Cin, Alog, Ai, Aj, Ak, out, d_ws, stream);
    } else if (ws_size >= ws_need(128)) {
        launch_all<128>(u, dt, Bin, Cin, Alog, Ai, Aj, Ak, out, d_ws, stream);
    } else {
        launch_all<64>(u, dt, Bin, Cin, Alog, Ai, Aj, Ak, out, d_ws, stream);
    }
}

// Round 9
// 151.832 us; speedup vs baseline: 1.1812x; 1.0573x over previous
//
#include <hip/hip_runtime.h>

#define BSZ   2
#define LSEQ  2048
#define DQ    512
#define SQ    4
#define EPSQ  1e-6f

typedef float nfloat4 __attribute__((ext_vector_type(4)));  // native vec for nontemporal
typedef float nfloat2 __attribute__((ext_vector_type(2)));  // VOP3P packed pair

__device__ __forceinline__ nfloat2 mk2(float x, float y) { nfloat2 v; v.x = x; v.y = y; return v; }

// ---------------- packed quaternion (pairs (r,i),(j,k); v_pk_fma_f32 path) ---
struct PQuat { nfloat2 ri, jk; };

__device__ __forceinline__ PQuat pq_of(const float4 v) {
    PQuat p; p.ri = mk2(v.x, v.y); p.jk = mk2(v.z, v.w); return p;
}
__device__ __forceinline__ float4 f4_of(const PQuat p) {
    return make_float4(p.ri.x, p.ri.y, p.jk.x, p.jk.y);
}

// o = a x b  (8 packed mul/fma vs 16 scalar)
__device__ __forceinline__ PQuat pqmul(const PQuat a, const PQuat b) {
    const float ar = a.ri.x, ai = a.ri.y, aj = a.jk.x, ak = a.jk.y;
    PQuat o;
    o.ri = ar*b.ri + ai*mk2(-b.ri.y,  b.ri.x)
         + aj*mk2(-b.jk.x,  b.jk.y) + ak*mk2(-b.jk.y, -b.jk.x);
    o.jk = ar*b.jk + ai*mk2(-b.jk.y,  b.jk.x)
         + aj*mk2( b.ri.x, -b.ri.y) + ak*mk2( b.ri.y,  b.ri.x);
    return o;
}

// o = a x b + c
__device__ __forceinline__ PQuat pqmuladd(const PQuat a, const PQuat b, const PQuat c) {
    const float ar = a.ri.x, ai = a.ri.y, aj = a.jk.x, ak = a.jk.y;
    PQuat o;
    o.ri = c.ri + ar*b.ri + ai*mk2(-b.ri.y,  b.ri.x)
         + aj*mk2(-b.jk.x,  b.jk.y) + ak*mk2(-b.jk.y, -b.jk.x);
    o.jk = c.jk + ar*b.jk + ai*mk2(-b.jk.y,  b.jk.x)
         + aj*mk2( b.ri.x, -b.ri.y) + ak*mk2( b.ri.y,  b.ri.x);
    return o;
}

// Cayley transition q and injection Bu (packed).
// q  = s*(1-|w|^2, 2wi, 2wj, 2wk), w = a*hA, s = 1/((1-wr)^2+|w_im|^2+eps)
// Bu = (a*s) * (conj(den) x B) x u, conj(den) = (1-wr, wi, wj, wk)
__device__ __forceinline__ void cayley_pk(const float a, const PQuat hA,
                                          const PQuat B, const PQuat U,
                                          PQuat& q, PQuat& Bu) {
    const nfloat2 w_ri = a * hA.ri;
    const nfloat2 w_jk = a * hA.jk;
    const float wr = w_ri.x, wi = w_ri.y;
    const float m  = wi*wi + w_jk.x*w_jk.x + w_jk.y*w_jk.y;
    const float e  = 1.0f - wr;
    const float dd = e*e + m + EPSQ;
    const float sv = __builtin_amdgcn_rcpf(dd);
    const float s2 = sv + sv;
    q.ri = mk2(sv * (1.0f - (wr*wr + m)), s2 * wi);
    q.jk = s2 * w_jk;
    PQuat cd; cd.ri = mk2(e, wi); cd.jk = w_jk;
    const PQuat cb = pqmul(cd, B);
    const float as = a * sv;
    PQuat dB; dB.ri = as * cb.ri; dB.jk = as * cb.jk;
    Bu = pqmul(dB, U);
}

__device__ __forceinline__ PQuat load_hA_pk(const float* __restrict__ Alog,
                                            const float* __restrict__ Ai,
                                            const float* __restrict__ Aj,
                                            const float* __restrict__ Ak, int idx) {
    PQuat p;
    p.ri = mk2(-0.5f * __expf(Alog[idx]), 0.5f * Ai[idx]);
    p.jk = mk2( 0.5f * Aj[idx],           0.5f * Ak[idx]);
    return p;
}

// ---------------- scalar quat (pass2 only — known-good path) ----------------
struct Quat { float r, i, j, k; };
__device__ __forceinline__ Quat qmul(const Quat a, const Quat b) {
    Quat o;
    o.r = a.r*b.r - a.i*b.i - a.j*b.j - a.k*b.k;
    o.i = a.r*b.i + a.i*b.r + a.j*b.k - a.k*b.j;
    o.j = a.r*b.j - a.i*b.k + a.j*b.r + a.k*b.i;
    o.k = a.r*b.k + a.i*b.j - a.j*b.i + a.k*b.r;
    return o;
}
__device__ __forceinline__ Quat qmuladd(const Quat a, const Quat b, const Quat c) {
    Quat o;
    o.r = c.r + a.r*b.r - a.i*b.i - a.j*b.j - a.k*b.k;
    o.i = c.i + a.r*b.i + a.i*b.r + a.j*b.k - a.k*b.j;
    o.j = c.j + a.r*b.j - a.i*b.k + a.j*b.r + a.k*b.i;
    o.k = c.k + a.r*b.k + a.i*b.j - a.j*b.i + a.k*b.r;
    return o;
}
__device__ __forceinline__ Quat q_of(const float4 v) { return Quat{v.x, v.y, v.z, v.w}; }
__device__ __forceinline__ float4 f4s_of(const Quat q) { return make_float4(q.r, q.i, q.j, q.k); }

// ---------------- pass 1: chunk summaries, 2 s-channels per thread -----------
// grid: (DQ/256, NCH, BSZ*2), block 256. z encodes (b, s-half).
// (256,6): ~85 VGPR cap, 6 waves/SIMD. (256,8) spilled (round 7: VGPR=32,
// +52MB scratch traffic). W layout: [b][s][c][d] float4.
template<int NCH>
__global__ __launch_bounds__(256, 6) void qssm_pass1(
    const float* __restrict__ u, const float* __restrict__ dt,
    const float* __restrict__ Bin,
    const float* __restrict__ Alog, const float* __restrict__ Ai,
    const float* __restrict__ Aj,   const float* __restrict__ Ak,
    float4* __restrict__ WQ, float4* __restrict__ WB)
{
    constexpr int CH = LSEQ / NCH;
    const int d  = blockIdx.x * 256 + threadIdx.x;
    const int c  = blockIdx.y;
    const int b  = blockIdx.z >> 1;
    const int s0 = (blockIdx.z & 1) * 2;   // this block handles s0, s0+1
    const int t0 = c * CH;

    PQuat hA[2];
    hA[0] = load_hA_pk(Alog, Ai, Aj, Ak, d*SQ + s0);
    hA[1] = load_hA_pk(Alog, Ai, Aj, Ak, d*SQ + s0 + 1);

    const int base = (b*LSEQ + t0);
    const float*  dtp = dt + (size_t)base*DQ + d;
    const float4* up  = (const float4*)u   + (size_t)base*DQ + d;
    const float4* Bp  = (const float4*)Bin + (size_t)base*SQ + s0;

    PQuat Q[2], Bc[2];
    // peel j = 0 (summary starts at identity)
    {
        const float a  = *dtp;
        const PQuat U  = pq_of(*up);
#pragma unroll
        for (int ss = 0; ss < 2; ++ss) {
            PQuat q, Bu;
            cayley_pk(a, hA[ss], pq_of(Bp[ss]), U, q, Bu);
            Q[ss] = q; Bc[ss] = Bu;
        }
        dtp += DQ; up += DQ; Bp += SQ;
    }
#pragma unroll 2
    for (int j = 1; j < CH; ++j) {
        const float a  = *dtp;
        const PQuat U  = pq_of(*up);
#pragma unroll
        for (int ss = 0; ss < 2; ++ss) {
            PQuat q, Bu;
            cayley_pk(a, hA[ss], pq_of(Bp[ss]), U, q, Bu);
            Bc[ss] = pqmuladd(q, Bc[ss], Bu);   // B' = q x B + Bu
            Q[ss]  = pqmul(q, Q[ss]);           // Q' = q x Q
        }
        dtp += DQ; up += DQ; Bp += SQ;
    }
#pragma unroll
    for (int ss = 0; ss < 2; ++ss) {
        const size_t idx = ((size_t)(b*SQ + s0 + ss)*NCH + c)*DQ + d;
        WQ[idx] = f4_of(Q[ss]);
        WB[idx] = f4_of(Bc[ss]);
    }
}

// ---------------- pass 2: hierarchical scan, coalesced over d ----------------
// Block = 16 consecutive d-channels of one (b,s); thread (i = t&15, g = t>>4)
// owns superchunk g (GS=16 chunks). Loads are 256B-contiguous over the 16 d's.
// Overwrites WB[c] with h at chunk c's start.
template<int NCH>
__global__ __launch_bounds__(256) void qssm_pass2(
    const float4* __restrict__ WQ, float4* __restrict__ WB)
{
    constexpr int GS = 16;          // chunks per superchunk
    constexpr int NG = NCH / GS;    // superchunks per channel
    __shared__ float4 QL[NG][16];
    __shared__ float4 BL[NG][16];
    __shared__ float4 HS[NG][16];

    const int t  = threadIdx.x;
    const int i  = t & 15;          // local channel (d offset)
    const int g  = t >> 4;          // superchunk
    const int bs = blockIdx.x >> 5;             // (b*SQ+s), 0..7
    const int d  = (blockIdx.x & 31) * 16 + i;  // 0..511
    const size_t chbase = (size_t)bs * NCH * DQ + d;

    // step 1: compose chunks c = g*GS .. g*GS+GS-1 (earlier-first)
    size_t idx = chbase + (size_t)(g * GS) * DQ;
    Quat Qa = q_of(WQ[idx]);
    Quat Ba = q_of(WB[idx]);
#pragma unroll
    for (int j = 1; j < GS; ++j) {
        idx += DQ;
        const Quat Qc = q_of(WQ[idx]);
        const Quat Bc = q_of(WB[idx]);
        Ba = qmuladd(Qc, Ba, Bc);
        Qa = qmul(Qc, Qa);
    }
    QL[g][i] = f4s_of(Qa);
    BL[g][i] = f4s_of(Ba);
    __syncthreads();

    // step 2: 16 threads scan superchunk summaries (h0 = 0)
    if (t < 16) {
        Quat h{0.f, 0.f, 0.f, 0.f};
#pragma unroll
        for (int gg = 0; gg < NG; ++gg) {
            HS[gg][t] = f4s_of(h);
            h = qmuladd(q_of(QL[gg][t]), h, q_of(BL[gg][t]));
        }
    }
    __syncthreads();

    // step 3: replay own superchunk, store h at each chunk start (in place)
    Quat h = q_of(HS[g][i]);
    idx = chbase + (size_t)(g * GS) * DQ;
#pragma unroll
    for (int j = 0; j < GS; ++j) {
        const Quat Qc = q_of(WQ[idx]);   // L2-hot re-read
        const Quat Bc = q_of(WB[idx]);
        WB[idx] = f4s_of(h);
        h = qmuladd(Qc, h, Bc);
        idx += DQ;
    }
}

// ---------------- pass 3: replay with correct h_start, emit output -----------
// grid: (DQ/128, NCH, BSZ), block 256 = 4 waves. Each wave: 32 d x 2 s-halves
// (lane = 32*sh + dl). Partial y reduced across halves via shfl_xor(32);
// lanes sh==0 store (contiguous addresses).
template<int NCH>
__global__ __launch_bounds__(256, 6) void qssm_pass3(
    const float* __restrict__ u, const float* __restrict__ dt,
    const float* __restrict__ Bin, const float* __restrict__ Cin,
    const float* __restrict__ Alog, const float* __restrict__ Ai,
    const float* __restrict__ Aj,   const float* __restrict__ Ak,
    const float4* __restrict__ WB, float* __restrict__ out)
{
    constexpr int CH = LSEQ / NCH;
    const int t    = threadIdx.x;
    const int lane = t & 63;
    const int wv   = t >> 6;
    const int dl   = lane & 31;
    const int sh   = lane >> 5;            // s-half: 0 or 1
    const int s0   = sh * 2;
    const int d = blockIdx.x * 128 + wv * 32 + dl;
    const int c = blockIdx.y;
    const int b = blockIdx.z;
    const int t0 = c * CH;

    PQuat hA[2];
    PQuat h[2];
#pragma unroll
    for (int ss = 0; ss < 2; ++ss) {
        hA[ss] = load_hA_pk(Alog, Ai, Aj, Ak, d*SQ + s0 + ss);
        h[ss] = pq_of(WB[((size_t)(b*SQ + s0 + ss)*NCH + c)*DQ + d]);
    }
    const int base = (b*LSEQ + t0);
    const float*  dtp  = dt + (size_t)base*DQ + d;
    const float4* up   = (const float4*)u   + (size_t)base*DQ + d;
    const float4* Bp   = (const float4*)Bin + (size_t)base*SQ + s0;
    const float4* Cp   = (const float4*)Cin + (size_t)base*SQ + s0;
    nfloat4*      outp = (nfloat4*)out + (size_t)base*DQ + d;

#pragma unroll 2
    for (int j = 0; j < CH; ++j) {
        const float a  = *dtp;
        const PQuat U  = pq_of(*up);
        PQuat y; y.ri = mk2(0.f, 0.f); y.jk = mk2(0.f, 0.f);
#pragma unroll
        for (int ss = 0; ss < 2; ++ss) {
            const PQuat Cq = pq_of(Cp[ss]);
            PQuat q, Bu;
            cayley_pk(a, hA[ss], pq_of(Bp[ss]), U, q, Bu);
            h[ss] = pqmuladd(q, h[ss], Bu);
            y = pqmuladd(Cq, h[ss], y);
        }
        // reduce partial y across the two s-halves (lanes l and l^32)
        float yr = y.ri.x + __shfl_xor(y.ri.x, 32);
        float yi = y.ri.y + __shfl_xor(y.ri.y, 32);
        float yj = y.jk.x + __shfl_xor(y.jk.x, 32);
        float yk = y.jk.y + __shfl_xor(y.jk.y, 32);
        if (sh == 0) {
            const nfloat4 yv = {yr, yi, yj, yk};
            __builtin_nontemporal_store(yv, outp);  // out never re-read
        }
        dtp += DQ; up += DQ; Bp += SQ; Cp += SQ; outp += DQ;
    }
}

template<int NCH>
static void launch_all(const float* u, const float* dt, const float* Bin,
                       const float* Cin, const float* Alog, const float* Ai,
                       const float* Aj, const float* Ak,
                       float* out, void* d_ws, hipStream_t stream) {
    const size_t elems = (size_t)BSZ * SQ * NCH * DQ;
    float4* WQ = (float4*)d_ws;
    float4* WB = WQ + elems;
    dim3 g1(DQ / 256, NCH, BSZ * 2);
    qssm_pass1<NCH><<<g1, 256, 0, stream>>>(u, dt, Bin, Alog, Ai, Aj, Ak, WQ, WB);
    qssm_pass2<NCH><<<(BSZ*SQ*DQ)/16, 16*(NCH/16), 0, stream>>>(WQ, WB);
    dim3 g3(DQ / 128, NCH, BSZ);
    qssm_pass3<NCH><<<g3, 256, 0, stream>>>(u, dt, Bin, Cin, Alog, Ai, Aj, Ak, WB, out);
}

extern "C" void kernel_launch(void* const* d_in, const int* in_sizes, int n_in,
                              void* d_out, int out_size, void* d_ws, size_t ws_size,
                              hipStream_t stream) {
    const float* u    = (const float*)d_in[0];
    const float* dt   = (const float*)d_in[1];
    const float* Bin  = (const float*)d_in[2];
    const float* Cin  = (const float*)d_in[3];
    const float* Alog = (const float*)d_in[4];
    const float* Ai   = (const float*)d_in[5];
    const float* Aj   = (const float*)d_in[6];
    const float* Ak   = (const float*)d_in[7];
    float* out = (float*)d_out;

    auto ws_need = [](int nch) -> size_t {
        return 2ull * BSZ * SQ * (size_t)nch * DQ * sizeof(float4);
    };
    if (ws_size >= ws_need(256)) {
        launch_all<256>(u, dt, Bin, Cin, Alog, Ai, Aj, Ak, out, d_ws, stream);
    } else if (ws_size >= ws_need(128)) {
        launch_all<128>(u, dt, Bin, Cin, Alog, Ai, Aj, Ak, out, d_ws, stream);
    } else {
        launch_all<64>(u, dt, Bin, Cin, Alog, Ai, Aj, Ak, out, d_ws, stream);
    }
}